// Round 8
// baseline (6000.476 us; speedup 1.0000x reference)
//
#include <hip/hip_runtime.h>
#include <hip/hip_bf16.h>
#include <math.h>

// Problem constants
constexpr int Bn  = 4;
constexpr int Nn  = 10000;
constexpr int En  = 320000;
constexpr int EAn = 80000;
constexpr int OUT_N = 2 * Bn * (EAn / 2);   // 320000 f32: mean(4x40000) | std(4x40000)

// ---------------------------------------------------------------------------
// Diagnostic sentinel (constant geometry — out_size is unreliable, round 6).
// ---------------------------------------------------------------------------
__global__ __launch_bounds__(256) void fill_sentinel(float* out, float v) {
    const int i = blockIdx.x * 256 + threadIdx.x;
    if (i < OUT_N) out[i] = v;
}

// ---------------------------------------------------------------------------
// Index decode: detect int64 vs int32 edge_index from the data, emit int32.
// (Rounds 2≡3 proved data is int32; detection kept as cheap insurance.)
// ---------------------------------------------------------------------------
__global__ __launch_bounds__(256) void decode_indices(const void* __restrict__ ei_raw,
                                                      const void* __restrict__ mask_raw,
                                                      int* __restrict__ ei32,
                                                      int* __restrict__ mask32) {
    __shared__ int is64;
    if (threadIdx.x == 0) {
        const long long* p = (const long long*)ei_raw;
        int ok = 1;
        for (int i = 0; i < 64; i++) {
            const long long v = p[i];
            if (v < 0 || v >= (long long)Nn) { ok = 0; break; }
        }
        is64 = ok;
    }
    __syncthreads();
    const int idx    = blockIdx.x * 256 + threadIdx.x;
    const int stride = gridDim.x * 256;
    if (is64) {
        for (int i = idx; i < 2 * En; i += stride)
            ei32[i] = (int)((const long long*)ei_raw)[i];
        for (int i = idx; i < EAn; i += stride)
            mask32[i] = (int)((const long long*)mask_raw)[i];
    } else {
        for (int i = idx; i < 2 * En; i += stride)
            ei32[i] = ((const int*)ei_raw)[i];
        for (int i = idx; i < EAn; i += stride)
            mask32[i] = ((const int*)mask_raw)[i];
    }
}

// ---------------------------------------------------------------------------
// DIRECT per-edge message + accumulate-scatter (np.add.at semantics):
//   pre  = [X[r] | X[s] | ea] @ W1 + b1        (K = 2*KN+16)
//   hid  = relu(pre)
//   msg  = hid @ W2 + b2
//   agg[r] += msg   (atomicAdd)
// Block: 256 threads, 16 edges. Thread = (col 0..127, half); 8 edges x 1 col.
// ---------------------------------------------------------------------------
template <int KN>
__global__ __launch_bounds__(256) void edge_msg_direct(const float* __restrict__ X,
                                                       const int* __restrict__ ei,
                                                       const float* __restrict__ edge_attr,
                                                       const float* __restrict__ W1,  // (2KN+16,128)
                                                       const float* __restrict__ b1,
                                                       const float* __restrict__ W2,  // (128,128)
                                                       const float* __restrict__ b2,
                                                       float* __restrict__ agg) {
    constexpr int RP = KN + 1;
    __shared__ int   ridx[16];
    __shared__ int   sidx[16];
    __shared__ float rrow[16 * RP];
    __shared__ float srow[16 * RP];
    __shared__ float eas[16 * 17];
    __shared__ float hid[16 * 129];

    const int b   = blockIdx.y;
    const int e0  = blockIdx.x * 16;
    const int tid = threadIdx.x;

    if (tid < 16) {
        ridx[tid] = ei[e0 + tid];
        sidx[tid] = ei[En + e0 + tid];
    }
    __syncthreads();

    for (int idx = tid; idx < 16 * KN; idx += 256) {
        const int e = idx / KN, k = idx - e * KN;
        rrow[e * RP + k] = X[((size_t)b * Nn + ridx[e]) * KN + k];
        srow[e * RP + k] = X[((size_t)b * Nn + sidx[e]) * KN + k];
    }
    {
        const int e = tid >> 4, k = tid & 15;
        eas[e * 17 + k] = edge_attr[((size_t)b * En + e0 + e) * 16 + k];
    }
    __syncthreads();

    const int col  = tid & 127;
    const int half = tid >> 7;

    float acc[8];
#pragma unroll
    for (int i = 0; i < 8; i++) acc[i] = b1[col];
    for (int k = 0; k < KN; k++) {
        const float w = W1[k * 128 + col];
#pragma unroll
        for (int i = 0; i < 8; i++) acc[i] += rrow[(half * 8 + i) * RP + k] * w;
    }
    for (int k = 0; k < KN; k++) {
        const float w = W1[(KN + k) * 128 + col];
#pragma unroll
        for (int i = 0; i < 8; i++) acc[i] += srow[(half * 8 + i) * RP + k] * w;
    }
#pragma unroll
    for (int k = 0; k < 16; k++) {
        const float w = W1[(2 * KN + k) * 128 + col];
#pragma unroll
        for (int i = 0; i < 8; i++) acc[i] += eas[(half * 8 + i) * 17 + k] * w;
    }
#pragma unroll
    for (int i = 0; i < 8; i++) hid[(half * 8 + i) * 129 + col] = fmaxf(acc[i], 0.f);
    __syncthreads();

    float o[8];
#pragma unroll
    for (int i = 0; i < 8; i++) o[i] = 0.f;
#pragma unroll 4
    for (int k = 0; k < 128; k++) {
        const float w = W2[k * 128 + col];
#pragma unroll
        for (int i = 0; i < 8; i++) o[i] += hid[(half * 8 + i) * 129 + k] * w;
    }
    const float bb = b2[col];
#pragma unroll
    for (int i = 0; i < 8; i++)
        atomicAdd(&agg[((size_t)b * Nn + ridx[half * 8 + i]) * 128 + col], o[i] + bb);
}

// ---------------------------------------------------------------------------
// h_out = relu([X, agg] @ uw + ub). In-place safe (rows staged in LDS first).
// ---------------------------------------------------------------------------
template <int KX>
__global__ __launch_bounds__(256) void node_update(const float* __restrict__ X,
                                                   const float* __restrict__ agg,
                                                   const float* __restrict__ uw,
                                                   const float* __restrict__ ub,
                                                   float* Hout) {
    constexpr int KT = KX + 128;
    constexpr int RP = KT + 1;
    __shared__ float xs[16 * RP];
    const int m0  = blockIdx.x * 16;
    const int tid = threadIdx.x;

    for (int idx = tid; idx < 16 * KX; idx += 256) {
        const int row = idx / KX, k = idx - row * KX;
        xs[row * RP + k] = X[(size_t)(m0 + row) * KX + k];
    }
    for (int idx = tid; idx < 16 * 128; idx += 256) {
        const int row = idx >> 7, k = idx & 127;
        xs[row * RP + KX + k] = agg[(size_t)(m0 + row) * 128 + k];
    }
    __syncthreads();

    const int col  = tid & 127;
    const int half = tid >> 7;
    float acc[8];
#pragma unroll
    for (int i = 0; i < 8; i++) acc[i] = ub[col];
#pragma unroll 4
    for (int k = 0; k < KT; k++) {
        const float w = uw[(size_t)k * 128 + col];
#pragma unroll
        for (int i = 0; i < 8; i++) acc[i] += xs[(half * 8 + i) * RP + k] * w;
    }
#pragma unroll
    for (int i = 0; i < 8; i++)
        Hout[(size_t)(m0 + half * 8 + i) * 128 + col] = fmaxf(acc[i], 0.f);
}

// ---------------------------------------------------------------------------
// Action head over masked edges: K=272 W1 GEMM, then 128->2 reduce.
// ---------------------------------------------------------------------------
__global__ __launch_bounds__(256) void action_head_direct(const float* __restrict__ H,   // (B*N,128)
                                                          const int* __restrict__ ei,
                                                          const float* __restrict__ edge_attr,
                                                          const int* __restrict__ mask,
                                                          const float* __restrict__ W1,  // (272,128)
                                                          const float* __restrict__ b1,
                                                          const float* __restrict__ w2,  // (128,2)
                                                          const float* __restrict__ b2,  // (2,)
                                                          float* __restrict__ act) {
    __shared__ int   ridx[16];
    __shared__ int   sidx[16];
    __shared__ int   eidx[16];
    __shared__ float rrow[16 * 129];
    __shared__ float srow[16 * 129];
    __shared__ float eas[16 * 17];
    __shared__ float hid[16 * 129];

    const int b   = blockIdx.y;
    const int j0  = blockIdx.x * 16;
    const int tid = threadIdx.x;

    if (tid < 16) {
        const int e = mask[j0 + tid];
        eidx[tid]   = e;
        ridx[tid]   = ei[e];
        sidx[tid]   = ei[En + e];
    }
    __syncthreads();

    for (int idx = tid; idx < 16 * 128; idx += 256) {
        const int e = idx >> 7, k = idx & 127;
        rrow[e * 129 + k] = H[((size_t)b * Nn + ridx[e]) * 128 + k];
        srow[e * 129 + k] = H[((size_t)b * Nn + sidx[e]) * 128 + k];
    }
    {
        const int e = tid >> 4, k = tid & 15;
        eas[e * 17 + k] = edge_attr[((size_t)b * En + eidx[e]) * 16 + k];
    }
    __syncthreads();

    const int col  = tid & 127;
    const int half = tid >> 7;
    float acc[8];
#pragma unroll
    for (int i = 0; i < 8; i++) acc[i] = b1[col];
    for (int k = 0; k < 128; k++) {
        const float w = W1[k * 128 + col];
#pragma unroll
        for (int i = 0; i < 8; i++) acc[i] += rrow[(half * 8 + i) * 129 + k] * w;
    }
    for (int k = 0; k < 128; k++) {
        const float w = W1[(128 + k) * 128 + col];
#pragma unroll
        for (int i = 0; i < 8; i++) acc[i] += srow[(half * 8 + i) * 129 + k] * w;
    }
#pragma unroll
    for (int k = 0; k < 16; k++) {
        const float w = W1[(256 + k) * 128 + col];
#pragma unroll
        for (int i = 0; i < 8; i++) acc[i] += eas[(half * 8 + i) * 17 + k] * w;
    }
#pragma unroll
    for (int i = 0; i < 8; i++) hid[(half * 8 + i) * 129 + col] = fmaxf(acc[i], 0.f);
    __syncthreads();

    // 16 edges x 16 threads: reduce 128 -> 2
    const int g    = tid >> 4;
    const int lane = tid & 15;
    float o0 = 0.f, o1 = 0.f;
#pragma unroll
    for (int k = lane; k < 128; k += 16) {
        const float hv = hid[g * 129 + k];
        o0 += hv * w2[k * 2 + 0];
        o1 += hv * w2[k * 2 + 1];
    }
#pragma unroll
    for (int m = 8; m >= 1; m >>= 1) {
        o0 += __shfl_xor(o0, m);
        o1 += __shfl_xor(o1, m);
    }
    if (lane == 0) {
        act[((size_t)b * EAn + j0 + g) * 2 + 0] = o0 + b2[0];
        act[((size_t)b * EAn + j0 + g) * 2 + 1] = o1 + b2[1];
    }
}

// ---------------------------------------------------------------------------
// Pair-mean + clip + exp. FLOAT32 output (round-7 finding): mean then std.
// ---------------------------------------------------------------------------
__global__ __launch_bounds__(256) void finalize(const float* __restrict__ act,
                                                float* __restrict__ out) {
    const int idx = blockIdx.x * 256 + threadIdx.x;
    constexpr int HALF = EAn / 2;          // 40000
    if (idx >= Bn * HALF) return;
    const int b = idx / HALF, t = idx - b * HALF;
    const float* a = &act[((size_t)b * EAn + 2 * t) * 2];
    const float m = 0.5f * (a[0] + a[2]);
    float l       = 0.5f * (a[1] + a[3]);
    l = fminf(fmaxf(l, -20.f), 2.f);
    out[idx]                     = m;
    out[Bn * HALF + idx]         = expf(l);
}

// ---------------------------------------------------------------------------
extern "C" void kernel_launch(void* const* d_in, const int* in_sizes, int n_in,
                              void* d_out, int out_size, void* d_ws, size_t ws_size,
                              hipStream_t stream) {
    (void)out_size;  // unreliable (round 6); all geometry is compile-time.

    // ---- Host-side guards ----
    static const long long want[20] = {
        (long long)Bn * Nn * 64, 2LL * En, (long long)Bn * En * 16, (long long)EAn,
        144 * 128, 128, 128 * 128, 128, 192 * 128, 128,
        272 * 128, 128, 128 * 128, 128, 256 * 128, 128,
        272 * 128, 128, 128 * 2, 2};
    bool sig_ok = (n_in == 20);
    if (sig_ok)
        for (int i = 0; i < 20; i++) sig_ok = sig_ok && (in_sizes[i] == want[i]);

    // Workspace layout (f32 words): agg | h | ei32 | mk32 ; act overlays agg.
    const size_t aggF = (size_t)Bn * Nn * 128;   // 5,120,000
    const size_t hF   = (size_t)Bn * Nn * 128;   // 5,120,000
    const size_t needBytes = (aggF + hF + 2 * En + EAn) * 4;

    const dim3 blk(256);
    if (!sig_ok) {
        fill_sentinel<<<(OUT_N + 255) / 256, blk, 0, stream>>>((float*)d_out, 5555.f);
        return;
    }
    if (ws_size < needBytes) {
        fill_sentinel<<<(OUT_N + 255) / 256, blk, 0, stream>>>((float*)d_out, 9999.f);
        return;
    }

    const float* nodes  = (const float*)d_in[0];
    const void*  ei_raw = d_in[1];
    const float* eattr  = (const float*)d_in[2];
    const void*  mk_raw = d_in[3];
    const float* g1_mw1 = (const float*)d_in[4];
    const float* g1_mb1 = (const float*)d_in[5];
    const float* g1_mw2 = (const float*)d_in[6];
    const float* g1_mb2 = (const float*)d_in[7];
    const float* g1_uw  = (const float*)d_in[8];
    const float* g1_ub  = (const float*)d_in[9];
    const float* g2_mw1 = (const float*)d_in[10];
    const float* g2_mb1 = (const float*)d_in[11];
    const float* g2_mw2 = (const float*)d_in[12];
    const float* g2_mb2 = (const float*)d_in[13];
    const float* g2_uw  = (const float*)d_in[14];
    const float* g2_ub  = (const float*)d_in[15];
    const float* a_w1   = (const float*)d_in[16];
    const float* a_b1   = (const float*)d_in[17];
    const float* a_w2   = (const float*)d_in[18];
    const float* a_b2   = (const float*)d_in[19];

    float* agg  = (float*)d_ws;
    float* h    = agg + aggF;
    int*   ei32 = (int*)(h + hF);
    int*   mk32 = ei32 + 2 * En;
    float* act  = agg;                           // overlay: agg dead by head time

    const int  nbNodes = (Bn * Nn) / 16;         // 2500
    const dim3 gEdge(En / 16, Bn);               // 20000 x 4
    const dim3 gAct(EAn / 16, Bn);               //  5000 x 4
    const size_t aggBytes = aggF * 4;

    decode_indices<<<2500, blk, 0, stream>>>(ei_raw, mk_raw, ei32, mk32);

    // ---- Layer 1 ----
    hipMemsetAsync(agg, 0, aggBytes, stream);
    edge_msg_direct<64><<<gEdge, blk, 0, stream>>>(nodes, ei32, eattr,
                                                   g1_mw1, g1_mb1, g1_mw2, g1_mb2, agg);
    node_update<64><<<nbNodes, blk, 0, stream>>>(nodes, agg, g1_uw, g1_ub, h);

    // ---- Layer 2 ----
    hipMemsetAsync(agg, 0, aggBytes, stream);
    edge_msg_direct<128><<<gEdge, blk, 0, stream>>>(h, ei32, eattr,
                                                    g2_mw1, g2_mb1, g2_mw2, g2_mb2, agg);
    node_update<128><<<nbNodes, blk, 0, stream>>>(h, agg, g2_uw, g2_ub, h);

    // ---- Action head ----
    action_head_direct<<<gAct, blk, 0, stream>>>(h, ei32, eattr, mk32,
                                                 a_w1, a_b1, a_w2, a_b2, act);
    finalize<<<(Bn * (EAn / 2) + 255) / 256, blk, 0, stream>>>(act, (float*)d_out);
}

// Round 9
// 1559.721 us; speedup vs baseline: 3.8471x; 3.8471x over previous
//
#include <hip/hip_runtime.h>
#include <hip/hip_bf16.h>
#include <math.h>

// Problem constants
constexpr int Bn  = 4;
constexpr int Nn  = 10000;
constexpr int En  = 320000;
constexpr int EAn = 80000;
constexpr int OUT_N = 2 * Bn * (EAn / 2);   // 320000 f32: mean | std

// ---------------------------------------------------------------------------
__global__ __launch_bounds__(256) void fill_sentinel(float* out, float v) {
    const int i = blockIdx.x * 256 + threadIdx.x;
    if (i < OUT_N) out[i] = v;
}

// ---------------------------------------------------------------------------
// Index decode (validated r8): int64-vs-int32 autodetect, emit int32.
// ---------------------------------------------------------------------------
__global__ __launch_bounds__(256) void decode_indices(const void* __restrict__ ei_raw,
                                                      const void* __restrict__ mask_raw,
                                                      int* __restrict__ ei32,
                                                      int* __restrict__ mask32) {
    __shared__ int is64;
    if (threadIdx.x == 0) {
        const long long* p = (const long long*)ei_raw;
        int ok = 1;
        for (int i = 0; i < 64; i++) {
            const long long v = p[i];
            if (v < 0 || v >= (long long)Nn) { ok = 0; break; }
        }
        is64 = ok;
    }
    __syncthreads();
    const int idx    = blockIdx.x * 256 + threadIdx.x;
    const int stride = gridDim.x * 256;
    if (is64) {
        for (int i = idx; i < 2 * En; i += stride)
            ei32[i] = (int)((const long long*)ei_raw)[i];
        for (int i = idx; i < EAn; i += stride)
            mask32[i] = (int)((const long long*)mask_raw)[i];
    } else {
        for (int i = idx; i < 2 * En; i += stride)
            ei32[i] = ((const int*)ei_raw)[i];
        for (int i = idx; i < EAn; i += stride)
            mask32[i] = ((const int*)mask_raw)[i];
    }
}

// ---------------------------------------------------------------------------
// degf[n] = # incoming edges (receiver count), as float. Batch-independent.
// ---------------------------------------------------------------------------
__global__ __launch_bounds__(256) void compute_deg(const int* __restrict__ ei,
                                                   float* __restrict__ degf) {
    const int e = blockIdx.x * 256 + threadIdx.x;
    if (e < En) atomicAdd(&degf[ei[e]], 1.f);
}

// ---------------------------------------------------------------------------
// P = X @ [Wr | Ws] -> (B*N, 256). Wr = W rows [0,KX), Ws = rows [KX,2KX).
// (validated structure from r2/r3 — numerically identical to direct path)
// ---------------------------------------------------------------------------
template <int KX>
__global__ __launch_bounds__(256) void precompute_P(const float* __restrict__ X,
                                                    const float* __restrict__ W,
                                                    float* __restrict__ P) {
    __shared__ float xs[16 * KX];
    const int m0  = blockIdx.x * 16;
    const int tid = threadIdx.x;

    for (int idx = tid; idx < 16 * KX; idx += 256)
        xs[idx] = X[(size_t)m0 * KX + idx];
    __syncthreads();

    const int col  = tid;
    const int side = col >> 7;
    const int jj   = col & 127;
    const float* Wp = W + (size_t)(side * KX) * 128 + jj;

    float acc[16];
#pragma unroll
    for (int i = 0; i < 16; i++) acc[i] = 0.f;

    for (int k = 0; k < KX; k++) {
        const float w = Wp[(size_t)k * 128];
#pragma unroll
        for (int i = 0; i < 16; i++) acc[i] += xs[i * KX + k] * w;
    }
#pragma unroll
    for (int i = 0; i < 16; i++) P[(size_t)(m0 + i) * 256 + col] = acc[i];
}

// ---------------------------------------------------------------------------
// Edge scatter (W2 hoisted out by linearity):
//   hid = relu(P_r[r] + P_s[s] + ea@We + b1);  aggH[r] += hid (atomic)
// Block: 16 edges x 128 cols, 256 threads; thread = (col, half), 8 edges.
// ---------------------------------------------------------------------------
__global__ __launch_bounds__(256) void edge_scatter(const float* __restrict__ P,
                                                    const int* __restrict__ ei,
                                                    const float* __restrict__ edge_attr,
                                                    const float* __restrict__ We,  // 16x128
                                                    const float* __restrict__ b1,
                                                    float* __restrict__ aggH) {
    __shared__ int   ridx[16];
    __shared__ int   sidx[16];
    __shared__ float eas[16 * 17];
    __shared__ float wes[16 * 128];

    const int b   = blockIdx.y;
    const int e0  = blockIdx.x * 16;
    const int tid = threadIdx.x;

    if (tid < 16) {
        ridx[tid] = ei[e0 + tid];
        sidx[tid] = ei[En + e0 + tid];
    }
    {
        const int e = tid >> 4, k = tid & 15;
        eas[e * 17 + k] = edge_attr[((size_t)b * En + e0 + e) * 16 + k];
    }
    for (int idx = tid; idx < 16 * 128; idx += 256) wes[idx] = We[idx];
    __syncthreads();

    const int col  = tid & 127;
    const int half = tid >> 7;
    const float bb = b1[col];

#pragma unroll
    for (int i = 0; i < 8; i++) {
        const int e = half * 8 + i;
        float a = bb + P[((size_t)b * Nn + ridx[e]) * 256 + col]
                     + P[((size_t)b * Nn + sidx[e]) * 256 + 128 + col];
#pragma unroll
        for (int k = 0; k < 16; k++) a += eas[e * 17 + k] * wes[k * 128 + col];
        atomicAdd(&aggH[((size_t)b * Nn + ridx[e]) * 128 + col], fmaxf(a, 0.f));
    }
}

// ---------------------------------------------------------------------------
// Fused node: agg = aggH@W2 + deg*b2 ; h' = relu([X, agg]@uw + ub).
// In-place safe (everything staged in LDS before Hout write).
// ---------------------------------------------------------------------------
template <int KX>
__global__ __launch_bounds__(256) void fused_node(const float* __restrict__ X,
                                                  const float* __restrict__ aggH,
                                                  const float* __restrict__ W2,
                                                  const float* __restrict__ b2,
                                                  const float* __restrict__ degf,
                                                  const float* __restrict__ uw,
                                                  const float* __restrict__ ub,
                                                  float* Hout) {
    __shared__ float ah[16 * 129];
    __shared__ float ag[16 * 129];
    __shared__ float xs[16 * (KX + 1)];
    __shared__ float dg[16];

    const int m0  = blockIdx.x * 16;     // Nn % 16 == 0 -> block never straddles batch
    const int tid = threadIdx.x;

    if (tid < 16) {
        const int row = m0 + tid;
        dg[tid] = degf[row - (row / Nn) * Nn];
    }
    for (int idx = tid; idx < 16 * 128; idx += 256) {
        const int row = idx >> 7, k = idx & 127;
        ah[row * 129 + k] = aggH[(size_t)(m0 + row) * 128 + k];
    }
    for (int idx = tid; idx < 16 * KX; idx += 256) {
        const int row = idx / KX, k = idx - row * KX;
        xs[row * (KX + 1) + k] = X[(size_t)(m0 + row) * KX + k];
    }
    __syncthreads();

    const int col  = tid & 127;
    const int half = tid >> 7;

    // agg = aggH @ W2 + deg*b2
    {
        const float b2c = b2[col];
        float acc[8];
#pragma unroll
        for (int i = 0; i < 8; i++) acc[i] = dg[half * 8 + i] * b2c;
#pragma unroll 4
        for (int k = 0; k < 128; k++) {
            const float w = W2[k * 128 + col];
#pragma unroll
            for (int i = 0; i < 8; i++) acc[i] += ah[(half * 8 + i) * 129 + k] * w;
        }
#pragma unroll
        for (int i = 0; i < 8; i++) ag[(half * 8 + i) * 129 + col] = acc[i];
    }
    __syncthreads();

    // h' = relu([X | agg] @ uw + ub)
    float acc[8];
#pragma unroll
    for (int i = 0; i < 8; i++) acc[i] = ub[col];
#pragma unroll 4
    for (int k = 0; k < KX; k++) {
        const float w = uw[(size_t)k * 128 + col];
#pragma unroll
        for (int i = 0; i < 8; i++) acc[i] += xs[(half * 8 + i) * (KX + 1) + k] * w;
    }
#pragma unroll 4
    for (int k = 0; k < 128; k++) {
        const float w = uw[(size_t)(KX + k) * 128 + col];
#pragma unroll
        for (int i = 0; i < 8; i++) acc[i] += ag[(half * 8 + i) * 129 + k] * w;
    }
#pragma unroll
    for (int i = 0; i < 8; i++)
        Hout[(size_t)(m0 + half * 8 + i) * 128 + col] = fmaxf(acc[i], 0.f);
}

// ---------------------------------------------------------------------------
// Action head via gathered Pa: hid = relu(Pa_r[r]+Pa_s[s]+ea@aWe+b1),
// then 128->2 shuffle reduce (validated r8 structure).
// ---------------------------------------------------------------------------
__global__ __launch_bounds__(256) void action_head_gather(const float* __restrict__ Pa,
                                                          const int* __restrict__ ei,
                                                          const float* __restrict__ edge_attr,
                                                          const int* __restrict__ mask,
                                                          const float* __restrict__ aWe,  // 16x128
                                                          const float* __restrict__ b1,
                                                          const float* __restrict__ w2,   // 128x2
                                                          const float* __restrict__ b2,   // 2
                                                          float* __restrict__ act) {
    __shared__ int   ridx[16];
    __shared__ int   sidx[16];
    __shared__ int   eidx[16];
    __shared__ float eas[16 * 17];
    __shared__ float wes[16 * 128];
    __shared__ float hid[16 * 129];

    const int b   = blockIdx.y;
    const int j0  = blockIdx.x * 16;
    const int tid = threadIdx.x;

    if (tid < 16) {
        const int e = mask[j0 + tid];
        eidx[tid]   = e;
        ridx[tid]   = ei[e];
        sidx[tid]   = ei[En + e];
    }
    for (int idx = tid; idx < 16 * 128; idx += 256) wes[idx] = aWe[idx];
    __syncthreads();
    {
        const int e = tid >> 4, k = tid & 15;
        eas[e * 17 + k] = edge_attr[((size_t)b * En + eidx[e]) * 16 + k];
    }
    __syncthreads();

    const int col  = tid & 127;
    const int half = tid >> 7;
    const float bb = b1[col];
#pragma unroll
    for (int i = 0; i < 8; i++) {
        const int e = half * 8 + i;
        float a = bb + Pa[((size_t)b * Nn + ridx[e]) * 256 + col]
                     + Pa[((size_t)b * Nn + sidx[e]) * 256 + 128 + col];
#pragma unroll
        for (int k = 0; k < 16; k++) a += eas[e * 17 + k] * wes[k * 128 + col];
        hid[e * 129 + col] = fmaxf(a, 0.f);
    }
    __syncthreads();

    const int g    = tid >> 4;
    const int lane = tid & 15;
    float o0 = 0.f, o1 = 0.f;
#pragma unroll
    for (int k = lane; k < 128; k += 16) {
        const float hv = hid[g * 129 + k];
        o0 += hv * w2[k * 2 + 0];
        o1 += hv * w2[k * 2 + 1];
    }
#pragma unroll
    for (int m = 8; m >= 1; m >>= 1) {
        o0 += __shfl_xor(o0, m);
        o1 += __shfl_xor(o1, m);
    }
    if (lane == 0) {
        act[((size_t)b * EAn + j0 + g) * 2 + 0] = o0 + b2[0];
        act[((size_t)b * EAn + j0 + g) * 2 + 1] = o1 + b2[1];
    }
}

// ---------------------------------------------------------------------------
// Pair-mean + clip + exp. FLOAT32 output: mean | std. (validated r8)
// ---------------------------------------------------------------------------
__global__ __launch_bounds__(256) void finalize(const float* __restrict__ act,
                                                float* __restrict__ out) {
    const int idx = blockIdx.x * 256 + threadIdx.x;
    constexpr int HALF = EAn / 2;
    if (idx >= Bn * HALF) return;
    const int b = idx / HALF, t = idx - b * HALF;
    const float* a = &act[((size_t)b * EAn + 2 * t) * 2];
    const float m = 0.5f * (a[0] + a[2]);
    float l       = 0.5f * (a[1] + a[3]);
    l = fminf(fmaxf(l, -20.f), 2.f);
    out[idx]             = m;
    out[Bn * HALF + idx] = expf(l);
}

// ---------------------------------------------------------------------------
extern "C" void kernel_launch(void* const* d_in, const int* in_sizes, int n_in,
                              void* d_out, int out_size, void* d_ws, size_t ws_size,
                              hipStream_t stream) {
    (void)out_size;  // unreliable (r6); geometry is compile-time.

    static const long long want[20] = {
        (long long)Bn * Nn * 64, 2LL * En, (long long)Bn * En * 16, (long long)EAn,
        144 * 128, 128, 128 * 128, 128, 192 * 128, 128,
        272 * 128, 128, 128 * 128, 128, 256 * 128, 128,
        272 * 128, 128, 128 * 2, 2};
    bool sig_ok = (n_in == 20);
    if (sig_ok)
        for (int i = 0; i < 20; i++) sig_ok = sig_ok && (in_sizes[i] == want[i]);

    // Workspace (f32 words): P | aggH | h | ei32 | mk32 | degf. act overlays aggH.
    const size_t PF   = (size_t)Bn * Nn * 256;   // 10,240,000
    const size_t aggF = (size_t)Bn * Nn * 128;   //  5,120,000
    const size_t hF   = (size_t)Bn * Nn * 128;   //  5,120,000
    const size_t needBytes = (PF + aggF + hF + 2 * En + EAn + Nn) * 4;  // ~85 MB

    const dim3 blk(256);
    if (!sig_ok) {
        fill_sentinel<<<(OUT_N + 255) / 256, blk, 0, stream>>>((float*)d_out, 5555.f);
        return;
    }
    if (ws_size < needBytes) {
        fill_sentinel<<<(OUT_N + 255) / 256, blk, 0, stream>>>((float*)d_out, 9999.f);
        return;
    }

    const float* nodes  = (const float*)d_in[0];
    const void*  ei_raw = d_in[1];
    const float* eattr  = (const float*)d_in[2];
    const void*  mk_raw = d_in[3];
    const float* g1_mw1 = (const float*)d_in[4];
    const float* g1_mb1 = (const float*)d_in[5];
    const float* g1_mw2 = (const float*)d_in[6];
    const float* g1_mb2 = (const float*)d_in[7];
    const float* g1_uw  = (const float*)d_in[8];
    const float* g1_ub  = (const float*)d_in[9];
    const float* g2_mw1 = (const float*)d_in[10];
    const float* g2_mb1 = (const float*)d_in[11];
    const float* g2_mw2 = (const float*)d_in[12];
    const float* g2_mb2 = (const float*)d_in[13];
    const float* g2_uw  = (const float*)d_in[14];
    const float* g2_ub  = (const float*)d_in[15];
    const float* a_w1   = (const float*)d_in[16];
    const float* a_b1   = (const float*)d_in[17];
    const float* a_w2   = (const float*)d_in[18];
    const float* a_b2   = (const float*)d_in[19];

    float* P    = (float*)d_ws;
    float* aggH = P + PF;
    float* h    = aggH + aggF;
    int*   ei32 = (int*)(h + hF);
    int*   mk32 = ei32 + 2 * En;
    float* degf = (float*)(mk32 + EAn);
    float* act  = aggH;                          // overlay: aggH dead by head time

    const int  nbNodes = (Bn * Nn) / 16;         // 2500
    const dim3 gEdge(En / 16, Bn);               // 20000 x 4
    const dim3 gAct(EAn / 16, Bn);               //  5000 x 4
    const size_t aggBytes = aggF * 4;

    decode_indices<<<2500, blk, 0, stream>>>(ei_raw, mk_raw, ei32, mk32);
    hipMemsetAsync(degf, 0, Nn * sizeof(float), stream);
    compute_deg<<<En / 256, blk, 0, stream>>>(ei32, degf);

    // ---- Layer 1 ----
    precompute_P<64><<<nbNodes, blk, 0, stream>>>(nodes, g1_mw1, P);
    hipMemsetAsync(aggH, 0, aggBytes, stream);
    edge_scatter<<<gEdge, blk, 0, stream>>>(P, ei32, eattr,
                                            g1_mw1 + 128 * 128, g1_mb1, aggH);
    fused_node<64><<<nbNodes, blk, 0, stream>>>(nodes, aggH, g1_mw2, g1_mb2, degf,
                                                g1_uw, g1_ub, h);

    // ---- Layer 2 ----
    precompute_P<128><<<nbNodes, blk, 0, stream>>>(h, g2_mw1, P);
    hipMemsetAsync(aggH, 0, aggBytes, stream);
    edge_scatter<<<gEdge, blk, 0, stream>>>(P, ei32, eattr,
                                            g2_mw1 + 256 * 128, g2_mb1, aggH);
    fused_node<128><<<nbNodes, blk, 0, stream>>>(h, aggH, g2_mw2, g2_mb2, degf,
                                                 g2_uw, g2_ub, h);

    // ---- Action head ----
    precompute_P<128><<<nbNodes, blk, 0, stream>>>(h, a_w1, P);
    action_head_gather<<<gAct, blk, 0, stream>>>(P, ei32, eattr, mk32,
                                                 a_w1 + 256 * 128, a_b1,
                                                 a_w2, a_b2, act);
    finalize<<<(Bn * (EAn / 2) + 255) / 256, blk, 0, stream>>>(act, (float*)d_out);
}